// Round 3
// baseline (951.175 us; speedup 1.0000x reference)
//
#include <hip/hip_runtime.h>

// ChildSumTreeLSTM, complete 8-ary tree, 7 levels, N=299593, MEM=150, IN=300.
// Level d occupies [(8^d-1)/7, (8^(d+1)-1)/7); children of p: 8p+1..8p+8.
// v3: 32x32x16 MFMA, A-frags gathered to registers (no x LDS), in-register
// parent reduction via shfl_xor(32), bf16 hsum, single barrier per block.

#define MEMD 150
#define IND  300
#define NINT 37449
#define CSTR 150      // c_out row stride (output layout)
#define FSTR 160      // fxb / hsum / fcsum row stride

typedef short bf16x8 __attribute__((ext_vector_type(8)));
typedef float f32x16 __attribute__((ext_vector_type(16)));

#define ZERO16 {0,0,0,0,0,0,0,0,0,0,0,0,0,0,0,0}

// ws layout (bytes)
#define FXB_OFF  0ul           // bf16 [NINT][160]
#define HSB_OFF  12000000ul    // bf16 [NINT][160]  (h_sum)
#define FCS_OFF  24000000ul    // f32  [NINT][160]  (sum f*c)
#define BPX_OFF  48000000ul    // bf16 B-frags x-side [4][5][19][64][8]
#define BPH_OFF  48400000ul    // bf16 B-frags h-side [4][5][10][64][8]

__device__ __forceinline__ float b2f(unsigned short u) {
    union { unsigned int i; float f; } v; v.i = ((unsigned int)u) << 16; return v.f;
}
__device__ __forceinline__ unsigned short f2b(float f) {
    union { float f; unsigned int i; } v; v.f = f;
    unsigned int x = v.i;
    x += 0x7fffu + ((x >> 16) & 1u);
    return (unsigned short)(x >> 16);
}
__device__ __forceinline__ float sigm(float x) {
    return __builtin_amdgcn_rcpf(1.0f + __expf(-x));
}
__device__ __forceinline__ float tanh_fast(float x) {
    float e = __expf(2.0f * x);
    return 1.0f - 2.0f * __builtin_amdgcn_rcpf(e + 1.0f);
}
// LDS swizzle: stride 384B/row, XOR row&7 into 16B-slot bits -> conflict-free b128
__device__ __forceinline__ int swz(int row, int off) {
    return row * 384 + (off ^ ((row & 7) << 4));
}

// gather one A-frag (8 bf16) of x for this lane; ks in [0,19), k=ks*16+hi*8
__device__ __forceinline__ bf16x8 ldx(const float* xr, int ks, int hi) {
    bf16x8 r;
    if (ks == 18 && hi) {           // k 296..303: only 296..299 exist
        float4 v = *(const float4*)(xr + 288);
        r[0]=f2b(v.x); r[1]=f2b(v.y); r[2]=f2b(v.z); r[3]=f2b(v.w);
        r[4]=0; r[5]=0; r[6]=0; r[7]=0;
    } else {
        float4 v0 = *(const float4*)(xr + ks * 16);
        float4 v1 = *(const float4*)(xr + ks * 16 + 4);
        r[0]=f2b(v0.x); r[1]=f2b(v0.y); r[2]=f2b(v0.z); r[3]=f2b(v0.w);
        r[4]=f2b(v1.x); r[5]=f2b(v1.y); r[6]=f2b(v1.z); r[7]=f2b(v1.w);
    }
    return r;
}

// ---- pack weights into 32x32x16 B-fragment order ----
__global__ void pack_w(const float* __restrict__ Wix, const float* __restrict__ Wox,
                       const float* __restrict__ Wux, const float* __restrict__ Wfx,
                       const float* __restrict__ Wih, const float* __restrict__ Woh,
                       const float* __restrict__ Wuh, const float* __restrict__ Wfh,
                       unsigned short* __restrict__ bpx, unsigned short* __restrict__ bph)
{
    const int total_x = 4 * 5 * 19 * 512;   // 194560
    const int total_h = 4 * 5 * 10 * 512;   // 102400
    for (int i = blockIdx.x * blockDim.x + threadIdx.x; i < total_x + total_h;
         i += gridDim.x * blockDim.x) {
        if (i < total_x) {
            int e = i & 7, lane = (i >> 3) & 63, rest = i >> 9;
            int ks = rest % 19; rest /= 19;
            int nt = rest % 5;  int g = rest / 5;
            int col = nt * 32 + (lane & 31);
            int k = ks * 16 + ((lane >> 5) << 3) + e;
            const float* W = (g == 0) ? Wix : (g == 1) ? Wox : (g == 2) ? Wux : Wfx;
            bpx[i] = f2b((col < MEMD && k < IND) ? W[col * IND + k] : 0.f);
        } else {
            int j = i - total_x;
            int e = j & 7, lane = (j >> 3) & 63, rest = j >> 9;
            int ks = rest % 10; rest /= 10;
            int nt = rest % 5;  int g = rest / 5;
            int col = nt * 32 + (lane & 31);
            int k = ks * 16 + ((lane >> 5) << 3) + e;
            const float* W = (g == 0) ? Wih : (g == 1) ? Woh : (g == 2) ? Wuh : Wfh;
            bph[j] = f2b((col < MEMD && k < MEMD) ? W[col * MEMD + k] : 0.f);
        }
    }
}

// ---- fx = Wfx*x + bfx for internal nodes ----
__global__ __launch_bounds__(512, 2)
void fx32(const int* __restrict__ tokens, const float* __restrict__ emb,
          const float* __restrict__ bfx, const unsigned short* __restrict__ bpx_u,
          unsigned short* __restrict__ fxb)
{
    const int tid = threadIdx.x, lane = tid & 63, w = tid >> 6;
    const int hi = lane >> 5, ln31 = lane & 31;
    const int tile0 = blockIdx.x * 64;
    const int rowsValid = min(64, NINT - tile0);
    const int mt = w >> 2;
    const int nu = ((w & 3) == 0) ? 2 : 1;
    const int arow = mt * 32 + ln31;
    const int tok = tokens[(arow < rowsValid) ? (tile0 + arow) : tile0];
    const float* xr = emb + (long)tok * IND + hi * 8;
    const bf16x8* BX = (const bf16x8*)bpx_u;

    for (int u = 0; u < nu; ++u) {
        const int nt = u ? 4 : (w & 3);
        f32x16 acc = ZERO16;
        bf16x8 a[10];
        #pragma unroll
        for (int ks = 0; ks < 10; ++ks) a[ks] = ldx(xr, ks, hi);
        #pragma unroll
        for (int ks = 0; ks < 10; ++ks) {
            bf16x8 b = BX[((3 * 5 + nt) * 19 + ks) * 64 + lane];
            acc = __builtin_amdgcn_mfma_f32_32x32x16_bf16(a[ks], b, acc, 0, 0, 0);
        }
        #pragma unroll
        for (int ks = 10; ks < 19; ++ks) a[ks - 10] = ldx(xr, ks, hi);
        #pragma unroll
        for (int ks = 10; ks < 19; ++ks) {
            bf16x8 b = BX[((3 * 5 + nt) * 19 + ks) * 64 + lane];
            acc = __builtin_amdgcn_mfma_f32_32x32x16_bf16(a[ks - 10], b, acc, 0, 0, 0);
        }
        const int col = nt * 32 + ln31;
        const bool colv = col < MEMD;
        const float bias = colv ? bfx[col] : 0.f;
        #pragma unroll
        for (int r = 0; r < 16; ++r) {
            int rloc = mt * 32 + (r & 3) + 8 * (r >> 2) + 4 * hi;
            if (rloc < rowsValid && colv)
                fxb[(long)(tile0 + rloc) * FSTR + col] = f2b(acc[r] + bias);
        }
    }
}

// ---- per-level kernel ----
template<bool INTERNAL>
__global__ __launch_bounds__(512, 2)
void level32(const int* __restrict__ tokens, const float* __restrict__ emb,
             const float* __restrict__ bix, const float* __restrict__ bih,
             const float* __restrict__ box_, const float* __restrict__ boh,
             const float* __restrict__ bux, const float* __restrict__ buh,
             const float* __restrict__ bfh,
             const unsigned short* __restrict__ bpx_u,
             const unsigned short* __restrict__ bph_u,
             const unsigned short* __restrict__ fxb,
             unsigned short* __restrict__ hsumb, float* __restrict__ fcsum,
             float* __restrict__ c_out, int base, int cnt, int writePar)
{
    __shared__ __align__(16) char hsL[64 * 384];   // h bf16, swizzled

    const int tid = threadIdx.x, lane = tid & 63, w = tid >> 6;
    const int hi = lane >> 5, ln31 = lane & 31;
    const int tile0 = blockIdx.x * 64;
    const int nodeBase = base + tile0;
    const int rowsValid = min(64, cnt - tile0);
    const int mt = w >> 2;                 // waves 0-3 -> mt0, 4-7 -> mt1
    const int nu = ((w & 3) == 0) ? 2 : 1; // waves 0,4 also take nt=4
    const int p0 = (nodeBase - 1) >> 3;

    const int arow = mt * 32 + ln31;
    const int anode = nodeBase + arow;
    const int tok = tokens[(arow < rowsValid) ? anode : nodeBase];
    const float* xr = emb + (long)tok * IND + hi * 8;
    const unsigned short* hr = hsumb + (long)anode * FSTR + hi * 8;
    const bf16x8* BX = (const bf16x8*)bpx_u;
    const bf16x8* BH = (const bf16x8*)bph_u;

    for (int u = 0; u < nu; ++u) {
        const int nt = u ? 4 : (w & 3);
        f32x16 ai = ZERO16, ao = ZERO16, au = ZERO16;
        bf16x8 a[10];
        // x-side K: 19 steps of 16
        #pragma unroll
        for (int ks = 0; ks < 10; ++ks) a[ks] = ldx(xr, ks, hi);
        #pragma unroll
        for (int ks = 0; ks < 10; ++ks) {
            bf16x8 b0 = BX[((0 * 5 + nt) * 19 + ks) * 64 + lane];
            bf16x8 b1 = BX[((1 * 5 + nt) * 19 + ks) * 64 + lane];
            bf16x8 b2 = BX[((2 * 5 + nt) * 19 + ks) * 64 + lane];
            ai = __builtin_amdgcn_mfma_f32_32x32x16_bf16(a[ks], b0, ai, 0, 0, 0);
            ao = __builtin_amdgcn_mfma_f32_32x32x16_bf16(a[ks], b1, ao, 0, 0, 0);
            au = __builtin_amdgcn_mfma_f32_32x32x16_bf16(a[ks], b2, au, 0, 0, 0);
        }
        #pragma unroll
        for (int ks = 10; ks < 19; ++ks) a[ks - 10] = ldx(xr, ks, hi);
        #pragma unroll
        for (int ks = 10; ks < 19; ++ks) {
            bf16x8 b0 = BX[((0 * 5 + nt) * 19 + ks) * 64 + lane];
            bf16x8 b1 = BX[((1 * 5 + nt) * 19 + ks) * 64 + lane];
            bf16x8 b2 = BX[((2 * 5 + nt) * 19 + ks) * 64 + lane];
            ai = __builtin_amdgcn_mfma_f32_32x32x16_bf16(a[ks - 10], b0, ai, 0, 0, 0);
            ao = __builtin_amdgcn_mfma_f32_32x32x16_bf16(a[ks - 10], b1, ao, 0, 0, 0);
            au = __builtin_amdgcn_mfma_f32_32x32x16_bf16(a[ks - 10], b2, au, 0, 0, 0);
        }
        if (INTERNAL) {  // h_sum side K: 10 steps (bf16 direct loads)
            #pragma unroll
            for (int ks = 0; ks < 10; ++ks) a[ks] = *(const bf16x8*)(hr + ks * 16);
            #pragma unroll
            for (int ks = 0; ks < 10; ++ks) {
                bf16x8 b0 = BH[((0 * 5 + nt) * 10 + ks) * 64 + lane];
                bf16x8 b1 = BH[((1 * 5 + nt) * 10 + ks) * 64 + lane];
                bf16x8 b2 = BH[((2 * 5 + nt) * 10 + ks) * 64 + lane];
                ai = __builtin_amdgcn_mfma_f32_32x32x16_bf16(a[ks], b0, ai, 0, 0, 0);
                ao = __builtin_amdgcn_mfma_f32_32x32x16_bf16(a[ks], b1, ao, 0, 0, 0);
                au = __builtin_amdgcn_mfma_f32_32x32x16_bf16(a[ks], b2, au, 0, 0, 0);
            }
        }
        // epilogue: gates, c, h, in-reg h_sum reduction
        const int col = nt * 32 + ln31;
        const bool colv = col < MEMD;
        const int cc = colv ? col : 0;
        const float bi = bix[cc] + bih[cc];
        const float bo = box_[cc] + boh[cc];
        const float bu = bux[cc] + buh[cc];
        float hp[4] = {0.f, 0.f, 0.f, 0.f};
        #pragma unroll
        for (int r = 0; r < 16; ++r) {
            int rloc = mt * 32 + (r & 3) + 8 * (r >> 2) + 4 * hi;
            int node = nodeBase + rloc;
            bool rv = rloc < rowsValid;
            float fc = 0.f;
            if (INTERNAL) fc = (rv && colv) ? fcsum[(long)node * FSTR + col] : 0.f;
            float iv = sigm(ai[r] + bi);
            float ov = sigm(ao[r] + bo);
            float uv = tanh_fast(au[r] + bu);
            float cv = iv * uv + fc;
            float hv = (rv && colv) ? ov * tanh_fast(cv) : 0.f;
            if (rv && colv) c_out[(long)node * CSTR + col] = cv;
            *(unsigned short*)(hsL + swz(rloc, col * 2)) = f2b(hv);
            hp[r >> 2] += hv;
        }
        if (writePar) {
            #pragma unroll
            for (int o = 0; o < 4; ++o) {
                float s = hp[o] + __shfl_xor(hp[o], 32);
                if (lane < 32 && colv && (mt * 32 + o * 8) < rowsValid)
                    hsumb[(long)(p0 + mt * 4 + o) * FSTR + col] = f2b(s);
            }
        }
    }
    __syncthreads();

    if (writePar) {
        for (int u = 0; u < nu; ++u) {
            const int nt = u ? 4 : (w & 3);
            f32x16 ff = ZERO16;
            #pragma unroll
            for (int ks = 0; ks < 10; ++ks) {
                bf16x8 a = *(const bf16x8*)(hsL + swz(mt * 32 + ln31, ks * 32 + hi * 16));
                bf16x8 b = BH[((3 * 5 + nt) * 10 + ks) * 64 + lane];
                ff = __builtin_amdgcn_mfma_f32_32x32x16_bf16(a, b, ff, 0, 0, 0);
            }
            const int col = nt * 32 + ln31;
            const bool colv = col < MEMD;
            const int cc = colv ? col : 0;
            const float bv = bfh[cc];
            #pragma unroll
            for (int o = 0; o < 4; ++o) {
                int p = p0 + mt * 4 + o;
                float fx = b2f(fxb[(long)p * FSTR + cc]);
                float fp = 0.f;
                #pragma unroll
                for (int q = 0; q < 4; ++q) {
                    int r = o * 4 + q;
                    int rloc = mt * 32 + q + 8 * o + 4 * hi;
                    int node = nodeBase + rloc;
                    float cvv = (rloc < rowsValid && colv)
                                ? c_out[(long)node * CSTR + col] : 0.f;
                    float f = sigm(ff[r] + bv + fx);
                    fp += f * cvv;
                }
                float s = fp + __shfl_xor(fp, 32);
                if (lane < 32 && colv && (mt * 32 + o * 8) < rowsValid)
                    fcsum[(long)p * FSTR + col] = s;
            }
        }
    }
}

extern "C" void kernel_launch(void* const* d_in, const int* in_sizes, int n_in,
                              void* d_out, int out_size, void* d_ws, size_t ws_size,
                              hipStream_t stream) {
    const int*   tokens = (const int*)d_in[0];
    const float* emb = (const float*)d_in[4];
    const float* Wix = (const float*)d_in[5];  const float* bix = (const float*)d_in[6];
    const float* Wih = (const float*)d_in[7];  const float* bih = (const float*)d_in[8];
    const float* Wfx = (const float*)d_in[9];  const float* bfx = (const float*)d_in[10];
    const float* Wfh = (const float*)d_in[11]; const float* bfh = (const float*)d_in[12];
    const float* Wox = (const float*)d_in[13]; const float* box_ = (const float*)d_in[14];
    const float* Woh = (const float*)d_in[15]; const float* boh = (const float*)d_in[16];
    const float* Wux = (const float*)d_in[17]; const float* bux = (const float*)d_in[18];
    const float* Wuh = (const float*)d_in[19]; const float* buh = (const float*)d_in[20];
    float* c_out = (float*)d_out;
    char* ws = (char*)d_ws;

    unsigned short* fxb   = (unsigned short*)(ws + FXB_OFF);
    unsigned short* hsumb = (unsigned short*)(ws + HSB_OFF);
    float*          fcs   = (float*)(ws + FCS_OFF);
    unsigned short* bpx   = (unsigned short*)(ws + BPX_OFF);
    unsigned short* bph   = (unsigned short*)(ws + BPH_OFF);

    pack_w<<<128, 512, 0, stream>>>(Wix, Wox, Wux, Wfx, Wih, Woh, Wuh, Wfh, bpx, bph);
    fx32<<<(NINT + 63) / 64, 512, 0, stream>>>(tokens, emb, bfx, bpx, fxb);

    static const int bases[7] = {0, 1, 9, 73, 585, 4681, 37449};
    static const int cnts[7]  = {1, 8, 64, 512, 4096, 32768, 262144};

    level32<false><<<cnts[6] / 64, 512, 0, stream>>>(
        tokens, emb, bix, bih, box_, boh, bux, buh, bfh,
        bpx, bph, fxb, hsumb, fcs, c_out, bases[6], cnts[6], 1);
    for (int d = 5; d >= 0; --d) {
        int grid = (cnts[d] + 63) / 64;
        level32<true><<<grid, 512, 0, stream>>>(
            tokens, emb, bix, bih, box_, boh, bux, buh, bfh,
            bpx, bph, fxb, hsumb, fcs, c_out, bases[d], cnts[d], (d > 0) ? 1 : 0);
    }
}

// Round 4
// 544.027 us; speedup vs baseline: 1.7484x; 1.7484x over previous
//
#include <hip/hip_runtime.h>

// ChildSumTreeLSTM, complete 8-ary tree, 7 levels, N=299593, MEM=150, IN=300.
// Level d occupies [(8^d-1)/7, (8^(d+1)-1)/7); children of p: 8p+1..8p+8.
// v4: verified 32x32x16 MFMA layouts from v3, but coalesced cooperative LDS
// staging for x/hsum (v3's per-lane global gather was the regression), c
// staged in LDS for coalesced writes + in-LDS reuse by the f*c reduction.

#define MEMD 150
#define IND  300
#define NINT 37449
#define FSTR 160

typedef short bf16x8 __attribute__((ext_vector_type(8)));
typedef float f32x16 __attribute__((ext_vector_type(16)));
#define ZERO16 {0,0,0,0,0,0,0,0,0,0,0,0,0,0,0,0}

// ws layout (bytes)
#define FXB_OFF  0ul           // bf16 [NINT][160]
#define HSB_OFF  12000000ul    // bf16 [NINT][160]  (h_sum)
#define FCS_OFF  24000000ul    // f32  [NINT][160]  (sum f*c)
#define BPX_OFF  48000000ul    // bf16 B-frags x-side [4][5][19][64][8]
#define BPH_OFF  48400000ul    // bf16 B-frags h-side [4][5][10][64][8]

__device__ __forceinline__ float b2f(unsigned short u) {
    union { unsigned int i; float f; } v; v.i = ((unsigned int)u) << 16; return v.f;
}
__device__ __forceinline__ unsigned short f2b(float f) {
    union { float f; unsigned int i; } v; v.f = f;
    unsigned int x = v.i;
    x += 0x7fffu + ((x >> 16) & 1u);
    return (unsigned short)(x >> 16);
}
__device__ __forceinline__ float sigm(float x) {
    return __builtin_amdgcn_rcpf(1.0f + __expf(-x));
}
__device__ __forceinline__ float tanh_fast(float x) {
    float e = __expf(2.0f * x);
    return 1.0f - 2.0f * __builtin_amdgcn_rcpf(e + 1.0f);
}

// ---- pack weights into 32x32x16 B-fragment order (verified v3) ----
__global__ void pack_w(const float* __restrict__ Wix, const float* __restrict__ Wox,
                       const float* __restrict__ Wux, const float* __restrict__ Wfx,
                       const float* __restrict__ Wih, const float* __restrict__ Woh,
                       const float* __restrict__ Wuh, const float* __restrict__ Wfh,
                       unsigned short* __restrict__ bpx, unsigned short* __restrict__ bph)
{
    const int total_x = 4 * 5 * 19 * 512;
    const int total_h = 4 * 5 * 10 * 512;
    for (int i = blockIdx.x * blockDim.x + threadIdx.x; i < total_x + total_h;
         i += gridDim.x * blockDim.x) {
        if (i < total_x) {
            int e = i & 7, lane = (i >> 3) & 63, rest = i >> 9;
            int ks = rest % 19; rest /= 19;
            int nt = rest % 5;  int g = rest / 5;
            int col = nt * 32 + (lane & 31);
            int k = ks * 16 + ((lane >> 5) << 3) + e;
            const float* W = (g == 0) ? Wix : (g == 1) ? Wox : (g == 2) ? Wux : Wfx;
            bpx[i] = f2b((col < MEMD && k < IND) ? W[col * IND + k] : 0.f);
        } else {
            int j = i - total_x;
            int e = j & 7, lane = (j >> 3) & 63, rest = j >> 9;
            int ks = rest % 10; rest /= 10;
            int nt = rest % 5;  int g = rest / 5;
            int col = nt * 32 + (lane & 31);
            int k = ks * 16 + ((lane >> 5) << 3) + e;
            const float* W = (g == 0) ? Wih : (g == 1) ? Woh : (g == 2) ? Wuh : Wfh;
            bph[j] = f2b((col < MEMD && k < MEMD) ? W[col * MEMD + k] : 0.f);
        }
    }
}

// ---- fx = Wfx*x + bfx for internal nodes ----
__global__ __launch_bounds__(256, 3)
void fx32(const int* __restrict__ tokens, const float* __restrict__ emb,
          const float* __restrict__ bfx, const unsigned short* __restrict__ bpx_u,
          unsigned short* __restrict__ fxb)
{
    __shared__ __align__(16) char sm0[20480];
    const int tid = threadIdx.x, lane = tid & 63, w = tid >> 6;
    const int hi = lane >> 5, ln31 = lane & 31;
    const int tile0 = blockIdx.x * 32;
    const int rowsValid = min(32, NINT - tile0);

    for (int i = tid; i < 32 * 76; i += 256) {
        int r = i / 76, q = i % 76;
        ushort4 p = {0, 0, 0, 0};
        if (q < 75) {
            int rr = (r < rowsValid) ? r : 0;
            int tok = tokens[tile0 + rr];
            float4 v = *(const float4*)(emb + (long)tok * IND + q * 4);
            p.x = f2b(v.x); p.y = f2b(v.y); p.z = f2b(v.z); p.w = f2b(v.w);
        }
        *(ushort4*)(sm0 + r * 640 + ((q * 8) ^ ((r & 7) << 4))) = p;
    }
    __syncthreads();

    const bf16x8* BX = (const bf16x8*)bpx_u;
    auto dofx = [&](int nt) {
        f32x16 acc = ZERO16;
        #pragma unroll
        for (int ks = 0; ks < 19; ++ks) {
            bf16x8 a = *(const bf16x8*)(sm0 + ln31 * 640 +
                                        ((ks * 32 + hi * 16) ^ ((ln31 & 7) << 4)));
            bf16x8 b = BX[((15 + nt) * 19 + ks) * 64 + lane];
            acc = __builtin_amdgcn_mfma_f32_32x32x16_bf16(a, b, acc, 0, 0, 0);
        }
        int col = nt * 32 + ln31;
        bool colv = col < MEMD;
        float bias = colv ? bfx[col] : 0.f;
        #pragma unroll
        for (int r = 0; r < 16; ++r) {
            int rloc = (r & 3) + 8 * (r >> 2) + 4 * hi;
            if (rloc < rowsValid && colv)
                fxb[(long)(tile0 + rloc) * FSTR + col] = f2b(acc[r] + bias);
        }
    };
    dofx(w);
    if (w == 0) dofx(4);
}

// ---- per-level kernel ----
template<bool INTERNAL>
__global__ __launch_bounds__(256, 3)
void level32(const int* __restrict__ tokens, const float* __restrict__ emb,
             const float* __restrict__ bix, const float* __restrict__ bih,
             const float* __restrict__ box_, const float* __restrict__ boh,
             const float* __restrict__ bux, const float* __restrict__ buh,
             const float* __restrict__ bfh,
             const unsigned short* __restrict__ bpx_u,
             const unsigned short* __restrict__ bph_u,
             const unsigned short* __restrict__ fxb,
             unsigned short* __restrict__ hsumb, float* __restrict__ fcsum,
             float* __restrict__ c_out, int base, int cnt, int writePar)
{
    // region0 [0,32768): phase A = xs 32x640B (+hsumL 32x384B at 20480);
    //                    phase B = hsL 32x384B (aliases xs, after barrier)
    // region1 [32768,52224): cL f32 [32][152]
    __shared__ __align__(16) char sm0[52224];
    float* cL = (float*)(sm0 + 32768);
    const int tid = threadIdx.x, lane = tid & 63, w = tid >> 6;
    const int hi = lane >> 5, ln31 = lane & 31;
    const int tile0 = blockIdx.x * 32;
    const int nodeBase = base + tile0;
    const int rowsValid = min(32, cnt - tile0);
    const int p0 = (nodeBase - 1) >> 3;

    // ---- stage x (coalesced) ----
    for (int i = tid; i < 32 * 76; i += 256) {
        int r = i / 76, q = i % 76;
        ushort4 p = {0, 0, 0, 0};
        if (q < 75) {
            int rr = (r < rowsValid) ? r : 0;
            int tok = tokens[nodeBase + rr];
            float4 v = *(const float4*)(emb + (long)tok * IND + q * 4);
            p.x = f2b(v.x); p.y = f2b(v.y); p.z = f2b(v.z); p.w = f2b(v.w);
        }
        *(ushort4*)(sm0 + r * 640 + ((q * 8) ^ ((r & 7) << 4))) = p;
    }
    if (INTERNAL) {   // stage h_sum (bf16, coalesced; pad cols multiply B-zeros)
        for (int i = tid; i < 32 * 40; i += 256) {
            int r = i / 40, q = i % 40;
            uint2 v = *(const uint2*)(hsumb + (long)(nodeBase + r) * FSTR + q * 4);
            *(uint2*)(sm0 + 20480 + r * 384 + ((q * 8) ^ ((r & 7) << 4))) = v;
        }
    }
    __syncthreads();

    const bf16x8* BX = (const bf16x8*)bpx_u;
    const bf16x8* BH = (const bf16x8*)bph_u;

    auto gates = [&](int nt, float* hv) {
        f32x16 ai = ZERO16, ao = ZERO16, au = ZERO16;
        #pragma unroll
        for (int ks = 0; ks < 19; ++ks) {
            bf16x8 a = *(const bf16x8*)(sm0 + ln31 * 640 +
                                        ((ks * 32 + hi * 16) ^ ((ln31 & 7) << 4)));
            bf16x8 b0 = BX[((0 * 5 + nt) * 19 + ks) * 64 + lane];
            bf16x8 b1 = BX[((1 * 5 + nt) * 19 + ks) * 64 + lane];
            bf16x8 b2 = BX[((2 * 5 + nt) * 19 + ks) * 64 + lane];
            ai = __builtin_amdgcn_mfma_f32_32x32x16_bf16(a, b0, ai, 0, 0, 0);
            ao = __builtin_amdgcn_mfma_f32_32x32x16_bf16(a, b1, ao, 0, 0, 0);
            au = __builtin_amdgcn_mfma_f32_32x32x16_bf16(a, b2, au, 0, 0, 0);
        }
        if (INTERNAL) {
            #pragma unroll
            for (int ks = 0; ks < 10; ++ks) {
                bf16x8 a = *(const bf16x8*)(sm0 + 20480 + ln31 * 384 +
                                            ((ks * 32 + hi * 16) ^ ((ln31 & 7) << 4)));
                bf16x8 b0 = BH[((0 * 5 + nt) * 10 + ks) * 64 + lane];
                bf16x8 b1 = BH[((1 * 5 + nt) * 10 + ks) * 64 + lane];
                bf16x8 b2 = BH[((2 * 5 + nt) * 10 + ks) * 64 + lane];
                ai = __builtin_amdgcn_mfma_f32_32x32x16_bf16(a, b0, ai, 0, 0, 0);
                ao = __builtin_amdgcn_mfma_f32_32x32x16_bf16(a, b1, ao, 0, 0, 0);
                au = __builtin_amdgcn_mfma_f32_32x32x16_bf16(a, b2, au, 0, 0, 0);
            }
        }
        const int col = nt * 32 + ln31;
        const bool colv = col < MEMD;
        const int cc = colv ? col : 0;
        const float bi = bix[cc] + bih[cc];
        const float bo = box_[cc] + boh[cc];
        const float bu = bux[cc] + buh[cc];
        float hp[4] = {0.f, 0.f, 0.f, 0.f};
        #pragma unroll
        for (int r = 0; r < 16; ++r) {
            int rloc = (r & 3) + 8 * (r >> 2) + 4 * hi;
            bool rv = rloc < rowsValid;
            float fc = 0.f;
            if (INTERNAL) fc = (rv && colv) ? fcsum[(long)(nodeBase + rloc) * FSTR + col] : 0.f;
            float iv = sigm(ai[r] + bi);
            float ov = sigm(ao[r] + bo);
            float uv = tanh_fast(au[r] + bu);
            float cv = iv * uv + fc;
            float h = (rv && colv) ? ov * tanh_fast(cv) : 0.f;
            if (colv) cL[rloc * 152 + col] = cv;
            hv[r] = h;
            hp[r >> 2] += h;
        }
        if (writePar) {
            #pragma unroll
            for (int o = 0; o < 4; ++o) {
                float s = hp[o] + __shfl_xor(hp[o], 32);
                if (lane < 32 && colv && o * 8 < rowsValid)
                    hsumb[(long)(p0 + o) * FSTR + col] = f2b(s);
            }
        }
    };
    float hvA[16], hvB[16];
    gates(w, hvA);
    if (w == 0) gates(4, hvB);
    __syncthreads();                       // xs/hsumL dead -> hsL may overwrite

    if (writePar) {
        auto wrh = [&](int nt, float* hv) {
            const int col = nt * 32 + ln31;
            #pragma unroll
            for (int r = 0; r < 16; ++r) {
                int rloc = (r & 3) + 8 * (r >> 2) + 4 * hi;
                *(unsigned short*)(sm0 + rloc * 384 + ((col * 2) ^ ((rloc & 7) << 4))) = f2b(hv[r]);
            }
        };
        wrh(w, hvA);
        if (w == 0) wrh(4, hvB);
    }
    // coalesced c write from cL
    for (int i = tid; i < 32 * 75; i += 256) {
        int r = i / 75, q = i % 75;
        if (r < rowsValid) {
            float2 v = *(const float2*)(cL + r * 152 + q * 2);
            *(float2*)(c_out + (long)(nodeBase + r) * MEMD + q * 2) = v;
        }
    }
    __syncthreads();

    if (writePar) {
        auto fh = [&](int nt) {
            f32x16 ff = ZERO16;
            #pragma unroll
            for (int ks = 0; ks < 10; ++ks) {
                bf16x8 a = *(const bf16x8*)(sm0 + ln31 * 384 +
                                            ((ks * 32 + hi * 16) ^ ((ln31 & 7) << 4)));
                bf16x8 b = BH[((15 + nt) * 10 + ks) * 64 + lane];
                ff = __builtin_amdgcn_mfma_f32_32x32x16_bf16(a, b, ff, 0, 0, 0);
            }
            const int col = nt * 32 + ln31;
            const bool colv = col < MEMD;
            const int cc = colv ? col : 0;
            const float bv = bfh[cc];
            #pragma unroll
            for (int o = 0; o < 4; ++o) {
                float fx = b2f(fxb[(long)(p0 + o) * FSTR + cc]);
                float fp = 0.f;
                #pragma unroll
                for (int q = 0; q < 4; ++q) {
                    int r = o * 4 + q;
                    int rloc = q + 8 * o + 4 * hi;
                    float cvv = (rloc < rowsValid && colv) ? cL[rloc * 152 + col] : 0.f;
                    fp += sigm(ff[r] + bv + fx) * cvv;
                }
                float s = fp + __shfl_xor(fp, 32);
                if (lane < 32 && colv && o * 8 < rowsValid)
                    fcsum[(long)(p0 + o) * FSTR + col] = s;
            }
        };
        fh(w);
        if (w == 0) fh(4);
    }
}

extern "C" void kernel_launch(void* const* d_in, const int* in_sizes, int n_in,
                              void* d_out, int out_size, void* d_ws, size_t ws_size,
                              hipStream_t stream) {
    const int*   tokens = (const int*)d_in[0];
    const float* emb = (const float*)d_in[4];
    const float* Wix = (const float*)d_in[5];  const float* bix = (const float*)d_in[6];
    const float* Wih = (const float*)d_in[7];  const float* bih = (const float*)d_in[8];
    const float* Wfx = (const float*)d_in[9];  const float* bfx = (const float*)d_in[10];
    const float* Wfh = (const float*)d_in[11]; const float* bfh = (const float*)d_in[12];
    const float* Wox = (const float*)d_in[13]; const float* box_ = (const float*)d_in[14];
    const float* Woh = (const float*)d_in[15]; const float* boh = (const float*)d_in[16];
    const float* Wux = (const float*)d_in[17]; const float* bux = (const float*)d_in[18];
    const float* Wuh = (const float*)d_in[19]; const float* buh = (const float*)d_in[20];
    float* c_out = (float*)d_out;
    char* ws = (char*)d_ws;

    unsigned short* fxb   = (unsigned short*)(ws + FXB_OFF);
    unsigned short* hsumb = (unsigned short*)(ws + HSB_OFF);
    float*          fcs   = (float*)(ws + FCS_OFF);
    unsigned short* bpx   = (unsigned short*)(ws + BPX_OFF);
    unsigned short* bph   = (unsigned short*)(ws + BPH_OFF);

    pack_w<<<128, 512, 0, stream>>>(Wix, Wox, Wux, Wfx, Wih, Woh, Wuh, Wfh, bpx, bph);
    fx32<<<(NINT + 31) / 32, 256, 0, stream>>>(tokens, emb, bfx, bpx, fxb);

    static const int bases[7] = {0, 1, 9, 73, 585, 4681, 37449};
    static const int cnts[7]  = {1, 8, 64, 512, 4096, 32768, 262144};

    level32<false><<<cnts[6] / 32, 256, 0, stream>>>(
        tokens, emb, bix, bih, box_, boh, bux, buh, bfh,
        bpx, bph, fxb, hsumb, fcs, c_out, bases[6], cnts[6], 1);
    for (int d = 5; d >= 0; --d) {
        int grid = (cnts[d] + 31) / 32;
        level32<true><<<grid, 256, 0, stream>>>(
            tokens, emb, bix, bih, box_, boh, bux, buh, bfh,
            bpx, bph, fxb, hsumb, fcs, c_out, bases[d], cnts[d], (d > 0) ? 1 : 0);
    }
}

// Round 5
// 499.464 us; speedup vs baseline: 1.9044x; 1.0892x over previous
//
#include <hip/hip_runtime.h>

// ChildSumTreeLSTM, complete 8-ary tree, 7 levels, N=299593, MEM=150, IN=300.
// Level d occupies [(8^d-1)/7, (8^(d+1)-1)/7); children of p: 8p+1..8p+8.
// v5: BM=64, 640 threads = 10 waves, one (mt,nt) MFMA tile-task per wave
// (perfect balance), 64KB LDS w/ phase aliasing -> 2 blocks/CU.

#define MEMD 150
#define IND  300
#define NINT 37449
#define FSTR 160

typedef short bf16x8 __attribute__((ext_vector_type(8)));
typedef float f32x16 __attribute__((ext_vector_type(16)));
#define ZERO16 {0,0,0,0,0,0,0,0,0,0,0,0,0,0,0,0}

// ws layout (bytes)
#define FXB_OFF  0ul           // bf16 [NINT][160]
#define HSB_OFF  12000000ul    // bf16 [NINT][160]  (h_sum)
#define FCS_OFF  24000000ul    // f32  [NINT][160]  (sum f*c)
#define BPX_OFF  48000000ul    // bf16 B-frags x-side [4][5][19][64][8]
#define BPH_OFF  48400000ul    // bf16 B-frags h-side [4][5][10][64][8]

__device__ __forceinline__ float b2f(unsigned short u) {
    union { unsigned int i; float f; } v; v.i = ((unsigned int)u) << 16; return v.f;
}
__device__ __forceinline__ unsigned short f2b(float f) {
    union { float f; unsigned int i; } v; v.f = f;
    unsigned int x = v.i;
    x += 0x7fffu + ((x >> 16) & 1u);
    return (unsigned short)(x >> 16);
}
__device__ __forceinline__ float sigm(float x) {
    return __builtin_amdgcn_rcpf(1.0f + __expf(-x));
}
__device__ __forceinline__ float tanh_fast(float x) {
    float e = __expf(2.0f * x);
    return 1.0f - 2.0f * __builtin_amdgcn_rcpf(e + 1.0f);
}

// ---- pack weights into 32x32x16 B-fragment order (verified) ----
__global__ void pack_w(const float* __restrict__ Wix, const float* __restrict__ Wox,
                       const float* __restrict__ Wux, const float* __restrict__ Wfx,
                       const float* __restrict__ Wih, const float* __restrict__ Woh,
                       const float* __restrict__ Wuh, const float* __restrict__ Wfh,
                       unsigned short* __restrict__ bpx, unsigned short* __restrict__ bph)
{
    const int total_x = 4 * 5 * 19 * 512;
    const int total_h = 4 * 5 * 10 * 512;
    for (int i = blockIdx.x * blockDim.x + threadIdx.x; i < total_x + total_h;
         i += gridDim.x * blockDim.x) {
        if (i < total_x) {
            int e = i & 7, lane = (i >> 3) & 63, rest = i >> 9;
            int ks = rest % 19; rest /= 19;
            int nt = rest % 5;  int g = rest / 5;
            int col = nt * 32 + (lane & 31);
            int k = ks * 16 + ((lane >> 5) << 3) + e;
            const float* W = (g == 0) ? Wix : (g == 1) ? Wox : (g == 2) ? Wux : Wfx;
            bpx[i] = f2b((col < MEMD && k < IND) ? W[col * IND + k] : 0.f);
        } else {
            int j = i - total_x;
            int e = j & 7, lane = (j >> 3) & 63, rest = j >> 9;
            int ks = rest % 10; rest /= 10;
            int nt = rest % 5;  int g = rest / 5;
            int col = nt * 32 + (lane & 31);
            int k = ks * 16 + ((lane >> 5) << 3) + e;
            const float* W = (g == 0) ? Wih : (g == 1) ? Woh : (g == 2) ? Wuh : Wfh;
            bph[j] = f2b((col < MEMD && k < MEMD) ? W[col * MEMD + k] : 0.f);
        }
    }
}

// ---- fx = Wfx*x + bfx for internal nodes: BM=64, 10 waves, 1 task each ----
__global__ __launch_bounds__(640, 4)
void fx32(const int* __restrict__ tokens, const float* __restrict__ emb,
          const float* __restrict__ bfx, const unsigned short* __restrict__ bpx_u,
          unsigned short* __restrict__ fxb)
{
    __shared__ __align__(16) char sm0[40960];
    const int tid = threadIdx.x, lane = tid & 63, w = tid >> 6;
    const int hi = lane >> 5, ln31 = lane & 31;
    const int tile0 = blockIdx.x * 64;
    const int rowsValid = min(64, NINT - tile0);
    const int mt = (w >= 5) ? 1 : 0, nt = w - mt * 5;

    for (int i = tid; i < 64 * 76; i += 640) {
        int r = i / 76, q = i % 76;
        ushort4 p = {0, 0, 0, 0};
        if (q < 75) {
            int rr = (r < rowsValid) ? r : 0;
            int tok = tokens[tile0 + rr];
            float4 v = *(const float4*)(emb + (long)tok * IND + q * 4);
            p.x = f2b(v.x); p.y = f2b(v.y); p.z = f2b(v.z); p.w = f2b(v.w);
        }
        *(ushort4*)(sm0 + r * 640 + ((q * 8) ^ ((r & 7) << 4))) = p;
    }
    __syncthreads();

    const bf16x8* BX = (const bf16x8*)bpx_u;
    const int row = mt * 32 + ln31;
    f32x16 acc = ZERO16;
    #pragma unroll
    for (int ks = 0; ks < 19; ++ks) {
        bf16x8 a = *(const bf16x8*)(sm0 + row * 640 +
                                    ((ks * 32 + hi * 16) ^ ((row & 7) << 4)));
        bf16x8 b = BX[((15 + nt) * 19 + ks) * 64 + lane];
        acc = __builtin_amdgcn_mfma_f32_32x32x16_bf16(a, b, acc, 0, 0, 0);
    }
    const int col = nt * 32 + ln31;
    const bool colv = col < MEMD;
    const float bias = colv ? bfx[col] : 0.f;
    #pragma unroll
    for (int r = 0; r < 16; ++r) {
        int rloc = mt * 32 + (r & 3) + 8 * (r >> 2) + 4 * hi;
        if (rloc < rowsValid && colv)
            fxb[(long)(tile0 + rloc) * FSTR + col] = f2b(acc[r] + bias);
    }
}

// ---- per-level kernel ----
template<bool INTERNAL>
__global__ __launch_bounds__(640, 5)
void level32(const int* __restrict__ tokens, const float* __restrict__ emb,
             const float* __restrict__ bix, const float* __restrict__ bih,
             const float* __restrict__ box_, const float* __restrict__ boh,
             const float* __restrict__ bux, const float* __restrict__ buh,
             const float* __restrict__ bfh,
             const unsigned short* __restrict__ bpx_u,
             const unsigned short* __restrict__ bph_u,
             const unsigned short* __restrict__ fxb,
             unsigned short* __restrict__ hsumb, float* __restrict__ fcsum,
             float* __restrict__ c_out, int base, int cnt, int writePar)
{
    // Phase A: xs [0,40960) 64 rows x 640B swizzled; hsumL [40960,65536) 64x384B.
    // Phase B (post-MFMA barrier): hsL [0,24576) 64x384B; cL f32 [24576,63488).
    __shared__ __align__(16) char sm0[65536];
    float* cL = (float*)(sm0 + 24576);
    const int tid = threadIdx.x, lane = tid & 63, w = tid >> 6;
    const int hi = lane >> 5, ln31 = lane & 31;
    const int tile0 = blockIdx.x * 64;
    const int nodeBase = base + tile0;
    const int rowsValid = min(64, cnt - tile0);
    const int p0 = (nodeBase - 1) >> 3;
    const int mt = (w >= 5) ? 1 : 0, nt = w - mt * 5;

    // ---- stage x (coalesced) ----
    for (int i = tid; i < 64 * 76; i += 640) {
        int r = i / 76, q = i % 76;
        ushort4 p = {0, 0, 0, 0};
        if (q < 75) {
            int rr = (r < rowsValid) ? r : 0;
            int tok = tokens[nodeBase + rr];
            float4 v = *(const float4*)(emb + (long)tok * IND + q * 4);
            p.x = f2b(v.x); p.y = f2b(v.y); p.z = f2b(v.z); p.w = f2b(v.w);
        }
        *(ushort4*)(sm0 + r * 640 + ((q * 8) ^ ((r & 7) << 4))) = p;
    }
    if (INTERNAL) {
        for (int i = tid; i < 64 * 40; i += 640) {
            int r = i / 40, q = i % 40;
            uint2 v = *(const uint2*)(hsumb + (long)(nodeBase + r) * FSTR + q * 4);
            *(uint2*)(sm0 + 40960 + r * 384 + ((q * 8) ^ ((r & 7) << 4))) = v;
        }
    }
    __syncthreads();

    const bf16x8* BX = (const bf16x8*)bpx_u;
    const bf16x8* BH = (const bf16x8*)bph_u;
    const int row = mt * 32 + ln31;

    // ---- MFMA gates ----
    f32x16 ai = ZERO16, ao = ZERO16, au = ZERO16;
    #pragma unroll
    for (int ks = 0; ks < 19; ++ks) {
        bf16x8 a = *(const bf16x8*)(sm0 + row * 640 +
                                    ((ks * 32 + hi * 16) ^ ((row & 7) << 4)));
        bf16x8 b0 = BX[((0 * 5 + nt) * 19 + ks) * 64 + lane];
        bf16x8 b1 = BX[((1 * 5 + nt) * 19 + ks) * 64 + lane];
        bf16x8 b2 = BX[((2 * 5 + nt) * 19 + ks) * 64 + lane];
        ai = __builtin_amdgcn_mfma_f32_32x32x16_bf16(a, b0, ai, 0, 0, 0);
        ao = __builtin_amdgcn_mfma_f32_32x32x16_bf16(a, b1, ao, 0, 0, 0);
        au = __builtin_amdgcn_mfma_f32_32x32x16_bf16(a, b2, au, 0, 0, 0);
    }
    if (INTERNAL) {
        #pragma unroll
        for (int ks = 0; ks < 10; ++ks) {
            bf16x8 a = *(const bf16x8*)(sm0 + 40960 + row * 384 +
                                        ((ks * 32 + hi * 16) ^ ((row & 7) << 4)));
            bf16x8 b0 = BH[((0 * 5 + nt) * 10 + ks) * 64 + lane];
            bf16x8 b1 = BH[((1 * 5 + nt) * 10 + ks) * 64 + lane];
            bf16x8 b2 = BH[((2 * 5 + nt) * 10 + ks) * 64 + lane];
            ai = __builtin_amdgcn_mfma_f32_32x32x16_bf16(a, b0, ai, 0, 0, 0);
            ao = __builtin_amdgcn_mfma_f32_32x32x16_bf16(a, b1, ao, 0, 0, 0);
            au = __builtin_amdgcn_mfma_f32_32x32x16_bf16(a, b2, au, 0, 0, 0);
        }
    }
    __syncthreads();   // xs/hsumL dead -> cL/hsL may be written

    // ---- epilogue: gates, c -> cL, h -> hsL, octet h_sum -> global ----
    {
        const int col = nt * 32 + ln31;
        const bool colv = col < MEMD;
        const int cc = colv ? col : 0;
        const float bi = bix[cc] + bih[cc];
        const float bo = box_[cc] + boh[cc];
        const float bu = bux[cc] + buh[cc];
        float hp[4] = {0.f, 0.f, 0.f, 0.f};
        #pragma unroll
        for (int r = 0; r < 16; ++r) {
            int rloc = mt * 32 + (r & 3) + 8 * (r >> 2) + 4 * hi;
            bool rv = rloc < rowsValid;
            float fc = 0.f;
            if (INTERNAL) fc = (rv && colv) ? fcsum[(long)(nodeBase + rloc) * FSTR + col] : 0.f;
            float iv = sigm(ai[r] + bi);
            float ov = sigm(ao[r] + bo);
            float uv = tanh_fast(au[r] + bu);
            float cv = iv * uv + fc;
            float h = (rv && colv) ? ov * tanh_fast(cv) : 0.f;
            if (colv) cL[rloc * 152 + col] = cv;
            if (writePar)
                *(unsigned short*)(sm0 + rloc * 384 + ((col * 2) ^ ((rloc & 7) << 4))) = f2b(h);
            hp[r >> 2] += h;
        }
        if (writePar) {
            #pragma unroll
            for (int o = 0; o < 4; ++o) {
                float s = hp[o] + __shfl_xor(hp[o], 32);
                if (lane < 32 && colv && (mt * 32 + o * 8) < rowsValid)
                    hsumb[(long)(p0 + mt * 4 + o) * FSTR + col] = f2b(s);
            }
        }
    }
    __syncthreads();   // cL, hsL complete

    // ---- coalesced c writeback ----
    for (int i = tid; i < 64 * 75; i += 640) {
        int r = i / 75, q = i % 75;
        if (r < rowsValid) {
            float2 v = *(const float2*)(cL + r * 152 + q * 2);
            *(float2*)(c_out + (long)(nodeBase + r) * MEMD + q * 2) = v;
        }
    }

    if (writePar) {
        // ---- fh = h @ Wfh^T ----
        f32x16 ff = ZERO16;
        #pragma unroll
        for (int ks = 0; ks < 10; ++ks) {
            bf16x8 a = *(const bf16x8*)(sm0 + row * 384 +
                                        ((ks * 32 + hi * 16) ^ ((row & 7) << 4)));
            bf16x8 b = BH[((15 + nt) * 10 + ks) * 64 + lane];
            ff = __builtin_amdgcn_mfma_f32_32x32x16_bf16(a, b, ff, 0, 0, 0);
        }
        const int col = nt * 32 + ln31;
        const bool colv = col < MEMD;
        const int cc = colv ? col : 0;
        const float bv = bfh[cc];
        #pragma unroll
        for (int o = 0; o < 4; ++o) {
            int p = p0 + mt * 4 + o;
            float fx = b2f(fxb[(long)p * FSTR + cc]);
            float fp = 0.f;
            #pragma unroll
            for (int q = 0; q < 4; ++q) {
                int r = o * 4 + q;
                int rloc = mt * 32 + q + 8 * o + 4 * hi;
                float cvv = (rloc < rowsValid && colv) ? cL[rloc * 152 + col] : 0.f;
                fp += sigm(ff[r] + bv + fx) * cvv;
            }
            float s = fp + __shfl_xor(fp, 32);
            if (lane < 32 && colv && (mt * 32 + o * 8) < rowsValid)
                fcsum[(long)p * FSTR + col] = s;
        }
    }
}

extern "C" void kernel_launch(void* const* d_in, const int* in_sizes, int n_in,
                              void* d_out, int out_size, void* d_ws, size_t ws_size,
                              hipStream_t stream) {
    const int*   tokens = (const int*)d_in[0];
    const float* emb = (const float*)d_in[4];
    const float* Wix = (const float*)d_in[5];  const float* bix = (const float*)d_in[6];
    const float* Wih = (const float*)d_in[7];  const float* bih = (const float*)d_in[8];
    const float* Wfx = (const float*)d_in[9];  const float* bfx = (const float*)d_in[10];
    const float* Wfh = (const float*)d_in[11]; const float* bfh = (const float*)d_in[12];
    const float* Wox = (const float*)d_in[13]; const float* box_ = (const float*)d_in[14];
    const float* Woh = (const float*)d_in[15]; const float* boh = (const float*)d_in[16];
    const float* Wux = (const float*)d_in[17]; const float* bux = (const float*)d_in[18];
    const float* Wuh = (const float*)d_in[19]; const float* buh = (const float*)d_in[20];
    float* c_out = (float*)d_out;
    char* ws = (char*)d_ws;

    unsigned short* fxb   = (unsigned short*)(ws + FXB_OFF);
    unsigned short* hsumb = (unsigned short*)(ws + HSB_OFF);
    float*          fcs   = (float*)(ws + FCS_OFF);
    unsigned short* bpx   = (unsigned short*)(ws + BPX_OFF);
    unsigned short* bph   = (unsigned short*)(ws + BPH_OFF);

    pack_w<<<128, 512, 0, stream>>>(Wix, Wox, Wux, Wfx, Wih, Woh, Wuh, Wfh, bpx, bph);
    fx32<<<(NINT + 63) / 64, 640, 0, stream>>>(tokens, emb, bfx, bpx, fxb);

    static const int bases[7] = {0, 1, 9, 73, 585, 4681, 37449};
    static const int cnts[7]  = {1, 8, 64, 512, 4096, 32768, 262144};

    level32<false><<<cnts[6] / 64, 640, 0, stream>>>(
        tokens, emb, bix, bih, box_, boh, bux, buh, bfh,
        bpx, bph, fxb, hsumb, fcs, c_out, bases[6], cnts[6], 1);
    for (int d = 5; d >= 0; --d) {
        int grid = (cnts[d] + 63) / 64;
        level32<true><<<grid, 640, 0, stream>>>(
            tokens, emb, bix, bih, box_, boh, bux, buh, bfh,
            bpx, bph, fxb, hsumb, fcs, c_out, bases[d], cnts[d], (d > 0) ? 1 : 0);
    }
}

// Round 6
// 472.490 us; speedup vs baseline: 2.0131x; 1.0571x over previous
//
#include <hip/hip_runtime.h>

// ChildSumTreeLSTM, complete 8-ary tree, 7 levels, N=299593, MEM=150, IN=300.
// Level d occupies [(8^d-1)/7, (8^(d+1)-1)/7); children of p: 8p+1..8p+8.
// v6: v5 + (a) explicit 2-deep prefetch of A/B in all MFMA loops,
// (b) c kept in registers for the fh phase + direct coalesced c stores
// (cL LDS buffer removed), (c) leaf LDS 40KB -> 3 blocks/CU.

#define MEMD 150
#define IND  300
#define NINT 37449
#define FSTR 160

typedef short bf16x8 __attribute__((ext_vector_type(8)));
typedef float f32x16 __attribute__((ext_vector_type(16)));
#define ZERO16 {0,0,0,0,0,0,0,0,0,0,0,0,0,0,0,0}

// ws layout (bytes)
#define FXB_OFF  0ul           // bf16 [NINT][160]
#define HSB_OFF  12000000ul    // bf16 [NINT][160]  (h_sum)
#define FCS_OFF  24000000ul    // f32  [NINT][160]  (sum f*c)
#define BPX_OFF  48000000ul    // bf16 B-frags x-side [4][5][19][64][8]
#define BPH_OFF  48400000ul    // bf16 B-frags h-side [4][5][10][64][8]

__device__ __forceinline__ float b2f(unsigned short u) {
    union { unsigned int i; float f; } v; v.i = ((unsigned int)u) << 16; return v.f;
}
__device__ __forceinline__ unsigned short f2b(float f) {
    union { float f; unsigned int i; } v; v.f = f;
    unsigned int x = v.i;
    x += 0x7fffu + ((x >> 16) & 1u);
    return (unsigned short)(x >> 16);
}
__device__ __forceinline__ float sigm(float x) {
    return __builtin_amdgcn_rcpf(1.0f + __expf(-x));
}
__device__ __forceinline__ float tanh_fast(float x) {
    float e = __expf(2.0f * x);
    return 1.0f - 2.0f * __builtin_amdgcn_rcpf(e + 1.0f);
}

// ---- pack weights into 32x32x16 B-fragment order (verified) ----
__global__ void pack_w(const float* __restrict__ Wix, const float* __restrict__ Wox,
                       const float* __restrict__ Wux, const float* __restrict__ Wfx,
                       const float* __restrict__ Wih, const float* __restrict__ Woh,
                       const float* __restrict__ Wuh, const float* __restrict__ Wfh,
                       unsigned short* __restrict__ bpx, unsigned short* __restrict__ bph)
{
    const int total_x = 4 * 5 * 19 * 512;
    const int total_h = 4 * 5 * 10 * 512;
    for (int i = blockIdx.x * blockDim.x + threadIdx.x; i < total_x + total_h;
         i += gridDim.x * blockDim.x) {
        if (i < total_x) {
            int e = i & 7, lane = (i >> 3) & 63, rest = i >> 9;
            int ks = rest % 19; rest /= 19;
            int nt = rest % 5;  int g = rest / 5;
            int col = nt * 32 + (lane & 31);
            int k = ks * 16 + ((lane >> 5) << 3) + e;
            const float* W = (g == 0) ? Wix : (g == 1) ? Wox : (g == 2) ? Wux : Wfx;
            bpx[i] = f2b((col < MEMD && k < IND) ? W[col * IND + k] : 0.f);
        } else {
            int j = i - total_x;
            int e = j & 7, lane = (j >> 3) & 63, rest = j >> 9;
            int ks = rest % 10; rest /= 10;
            int nt = rest % 5;  int g = rest / 5;
            int col = nt * 32 + (lane & 31);
            int k = ks * 16 + ((lane >> 5) << 3) + e;
            const float* W = (g == 0) ? Wih : (g == 1) ? Woh : (g == 2) ? Wuh : Wfh;
            bph[j] = f2b((col < MEMD && k < MEMD) ? W[col * MEMD + k] : 0.f);
        }
    }
}

#define LDA64(base, stride, ks) \
    (*(const bf16x8*)((base) + row * (stride) + ((((ks) * 32 + hi * 16)) ^ ((row & 7) << 4))))

// ---- fx = Wfx*x + bfx for internal nodes ----
__global__ __launch_bounds__(640, 2)
void fx32(const int* __restrict__ tokens, const float* __restrict__ emb,
          const float* __restrict__ bfx, const unsigned short* __restrict__ bpx_u,
          unsigned short* __restrict__ fxb)
{
    __shared__ __align__(16) char sm0[40960];
    const int tid = threadIdx.x, lane = tid & 63, w = tid >> 6;
    const int hi = lane >> 5, ln31 = lane & 31;
    const int tile0 = blockIdx.x * 64;
    const int rowsValid = min(64, NINT - tile0);
    const int mt = (w >= 5) ? 1 : 0, nt = w - mt * 5;

    for (int i = tid; i < 64 * 76; i += 640) {
        int r = i / 76, q = i % 76;
        ushort4 p = {0, 0, 0, 0};
        if (q < 75) {
            int rr = (r < rowsValid) ? r : 0;
            int tok = tokens[tile0 + rr];
            float4 v = *(const float4*)(emb + (long)tok * IND + q * 4);
            p.x = f2b(v.x); p.y = f2b(v.y); p.z = f2b(v.z); p.w = f2b(v.w);
        }
        *(ushort4*)(sm0 + r * 640 + ((q * 8) ^ ((r & 7) << 4))) = p;
    }
    __syncthreads();

    const bf16x8* BX = (const bf16x8*)bpx_u;
    const int row = mt * 32 + ln31;
    f32x16 acc = ZERO16;
    bf16x8 aC = LDA64(sm0, 640, 0);
    bf16x8 bC = BX[((15 + nt) * 19 + 0) * 64 + lane];
    #pragma unroll
    for (int ks = 0; ks < 19; ++ks) {
        bf16x8 aN, bN;
        if (ks < 18) {
            aN = LDA64(sm0, 640, ks + 1);
            bN = BX[((15 + nt) * 19 + ks + 1) * 64 + lane];
        }
        acc = __builtin_amdgcn_mfma_f32_32x32x16_bf16(aC, bC, acc, 0, 0, 0);
        aC = aN; bC = bN;
    }
    const int col = nt * 32 + ln31;
    const bool colv = col < MEMD;
    const float bias = colv ? bfx[col] : 0.f;
    #pragma unroll
    for (int r = 0; r < 16; ++r) {
        int rloc = mt * 32 + (r & 3) + 8 * (r >> 2) + 4 * hi;
        if (rloc < rowsValid && colv)
            fxb[(long)(tile0 + rloc) * FSTR + col] = f2b(acc[r] + bias);
    }
}

// ---- per-level kernel ----
template<bool INTERNAL>
__global__ __launch_bounds__(640, 2)
void level32(const int* __restrict__ tokens, const float* __restrict__ emb,
             const float* __restrict__ bix, const float* __restrict__ bih,
             const float* __restrict__ box_, const float* __restrict__ boh,
             const float* __restrict__ bux, const float* __restrict__ buh,
             const float* __restrict__ bfh,
             const unsigned short* __restrict__ bpx_u,
             const unsigned short* __restrict__ bph_u,
             const unsigned short* __restrict__ fxb,
             unsigned short* __restrict__ hsumb, float* __restrict__ fcsum,
             float* __restrict__ c_out, int base, int cnt, int writePar)
{
    // Phase A: xs [0,40960) 64x640B swizzled; (INTERNAL) hsumL [40960,65536) 64x384B.
    // Phase B (after MFMA barrier): hsL [0,24576) 64x384B (aliases xs).
    __shared__ __align__(16) char sm0[INTERNAL ? 65536 : 40960];
    const int tid = threadIdx.x, lane = tid & 63, w = tid >> 6;
    const int hi = lane >> 5, ln31 = lane & 31;
    const int tile0 = blockIdx.x * 64;
    const int nodeBase = base + tile0;
    const int rowsValid = min(64, cnt - tile0);
    const int p0 = (nodeBase - 1) >> 3;
    const int mt = (w >= 5) ? 1 : 0, nt = w - mt * 5;

    // ---- stage x (coalesced) ----
    for (int i = tid; i < 64 * 76; i += 640) {
        int r = i / 76, q = i % 76;
        ushort4 p = {0, 0, 0, 0};
        if (q < 75) {
            int rr = (r < rowsValid) ? r : 0;
            int tok = tokens[nodeBase + rr];
            float4 v = *(const float4*)(emb + (long)tok * IND + q * 4);
            p.x = f2b(v.x); p.y = f2b(v.y); p.z = f2b(v.z); p.w = f2b(v.w);
        }
        *(ushort4*)(sm0 + r * 640 + ((q * 8) ^ ((r & 7) << 4))) = p;
    }
    if (INTERNAL) {
        for (int i = tid; i < 64 * 40; i += 640) {
            int r = i / 40, q = i % 40;
            uint2 v = *(const uint2*)(hsumb + (long)(nodeBase + r) * FSTR + q * 4);
            *(uint2*)(sm0 + 40960 + r * 384 + ((q * 8) ^ ((r & 7) << 4))) = v;
        }
    }
    __syncthreads();

    const bf16x8* BX = (const bf16x8*)bpx_u;
    const bf16x8* BH = (const bf16x8*)bph_u;
    const int row = mt * 32 + ln31;

    // ---- MFMA gates (2-deep prefetched) ----
    f32x16 ai = ZERO16, ao = ZERO16, au = ZERO16;
    {
        bf16x8 aC = LDA64(sm0, 640, 0);
        bf16x8 b0C = BX[((0 * 5 + nt) * 19 + 0) * 64 + lane];
        bf16x8 b1C = BX[((1 * 5 + nt) * 19 + 0) * 64 + lane];
        bf16x8 b2C = BX[((2 * 5 + nt) * 19 + 0) * 64 + lane];
        #pragma unroll
        for (int ks = 0; ks < 19; ++ks) {
            bf16x8 aN, b0N, b1N, b2N;
            if (ks < 18) {
                aN  = LDA64(sm0, 640, ks + 1);
                b0N = BX[((0 * 5 + nt) * 19 + ks + 1) * 64 + lane];
                b1N = BX[((1 * 5 + nt) * 19 + ks + 1) * 64 + lane];
                b2N = BX[((2 * 5 + nt) * 19 + ks + 1) * 64 + lane];
            }
            ai = __builtin_amdgcn_mfma_f32_32x32x16_bf16(aC, b0C, ai, 0, 0, 0);
            ao = __builtin_amdgcn_mfma_f32_32x32x16_bf16(aC, b1C, ao, 0, 0, 0);
            au = __builtin_amdgcn_mfma_f32_32x32x16_bf16(aC, b2C, au, 0, 0, 0);
            aC = aN; b0C = b0N; b1C = b1N; b2C = b2N;
        }
    }
    if (INTERNAL) {
        const char* hb = sm0 + 40960;
        bf16x8 aC = LDA64(hb, 384, 0);
        bf16x8 b0C = BH[((0 * 5 + nt) * 10 + 0) * 64 + lane];
        bf16x8 b1C = BH[((1 * 5 + nt) * 10 + 0) * 64 + lane];
        bf16x8 b2C = BH[((2 * 5 + nt) * 10 + 0) * 64 + lane];
        #pragma unroll
        for (int ks = 0; ks < 10; ++ks) {
            bf16x8 aN, b0N, b1N, b2N;
            if (ks < 9) {
                aN  = LDA64(hb, 384, ks + 1);
                b0N = BH[((0 * 5 + nt) * 10 + ks + 1) * 64 + lane];
                b1N = BH[((1 * 5 + nt) * 10 + ks + 1) * 64 + lane];
                b2N = BH[((2 * 5 + nt) * 10 + ks + 1) * 64 + lane];
            }
            ai = __builtin_amdgcn_mfma_f32_32x32x16_bf16(aC, b0C, ai, 0, 0, 0);
            ao = __builtin_amdgcn_mfma_f32_32x32x16_bf16(aC, b1C, ao, 0, 0, 0);
            au = __builtin_amdgcn_mfma_f32_32x32x16_bf16(aC, b2C, au, 0, 0, 0);
            aC = aN; b0C = b0N; b1C = b1N; b2C = b2N;
        }
    }
    __syncthreads();   // xs/hsumL dead -> hsL may be written

    // ---- epilogue: gates; c -> global (coalesced 128B) + regs; h -> hsL ----
    float cvv[16];
    {
        const int col = nt * 32 + ln31;
        const bool colv = col < MEMD;
        const int cc = colv ? col : 0;
        const float bi = bix[cc] + bih[cc];
        const float bo = box_[cc] + boh[cc];
        const float bu = bux[cc] + buh[cc];
        float hp[4] = {0.f, 0.f, 0.f, 0.f};
        #pragma unroll
        for (int r = 0; r < 16; ++r) {
            int rloc = mt * 32 + (r & 3) + 8 * (r >> 2) + 4 * hi;
            bool rv = rloc < rowsValid;
            float fc = 0.f;
            if (INTERNAL) fc = (rv && colv) ? fcsum[(long)(nodeBase + rloc) * FSTR + col] : 0.f;
            float iv = sigm(ai[r] + bi);
            float ov = sigm(ao[r] + bo);
            float uv = tanh_fast(au[r] + bu);
            float cv = iv * uv + fc;
            float h = (rv && colv) ? ov * tanh_fast(cv) : 0.f;
            cvv[r] = (rv && colv) ? cv : 0.f;
            if (rv && colv) c_out[(long)(nodeBase + rloc) * MEMD + col] = cv;
            if (writePar)
                *(unsigned short*)(sm0 + rloc * 384 + ((col * 2) ^ ((rloc & 7) << 4))) = f2b(h);
            hp[r >> 2] += h;
        }
        if (writePar) {
            #pragma unroll
            for (int o = 0; o < 4; ++o) {
                float s = hp[o] + __shfl_xor(hp[o], 32);
                if (lane < 32 && colv && (mt * 32 + o * 8) < rowsValid)
                    hsumb[(long)(p0 + mt * 4 + o) * FSTR + col] = f2b(s);
            }
        }
    }
    __syncthreads();   // hsL complete

    if (writePar) {
        // ---- fh = h @ Wfh^T (prefetched); f*c uses register cvv ----
        f32x16 ff = ZERO16;
        {
            bf16x8 aC = LDA64(sm0, 384, 0);
            bf16x8 bC = BH[((15 + nt) * 10 + 0) * 64 + lane];
            #pragma unroll
            for (int ks = 0; ks < 10; ++ks) {
                bf16x8 aN, bN;
                if (ks < 9) {
                    aN = LDA64(sm0, 384, ks + 1);
                    bN = BH[((15 + nt) * 10 + ks + 1) * 64 + lane];
                }
                ff = __builtin_amdgcn_mfma_f32_32x32x16_bf16(aC, bC, ff, 0, 0, 0);
                aC = aN; bC = bN;
            }
        }
        const int col = nt * 32 + ln31;
        const bool colv = col < MEMD;
        const int cc = colv ? col : 0;
        const float bv = bfh[cc];
        #pragma unroll
        for (int o = 0; o < 4; ++o) {
            int p = p0 + mt * 4 + o;
            float fx = b2f(fxb[(long)p * FSTR + cc]);
            float fp = 0.f;
            #pragma unroll
            for (int q = 0; q < 4; ++q) {
                int r = o * 4 + q;
                fp += sigm(ff[r] + bv + fx) * cvv[r];
            }
            float s = fp + __shfl_xor(fp, 32);
            if (lane < 32 && colv && (mt * 32 + o * 8) < rowsValid)
                fcsum[(long)p * FSTR + col] = s;
        }
    }
}

extern "C" void kernel_launch(void* const* d_in, const int* in_sizes, int n_in,
                              void* d_out, int out_size, void* d_ws, size_t ws_size,
                              hipStream_t stream) {
    const int*   tokens = (const int*)d_in[0];
    const float* emb = (const float*)d_in[4];
    const float* Wix = (const float*)d_in[5];  const float* bix = (const float*)d_in[6];
    const float* Wih = (const float*)d_in[7];  const float* bih = (const float*)d_in[8];
    const float* Wfx = (const float*)d_in[9];  const float* bfx = (const float*)d_in[10];
    const float* Wfh = (const float*)d_in[11]; const float* bfh = (const float*)d_in[12];
    const float* Wox = (const float*)d_in[13]; const float* box_ = (const float*)d_in[14];
    const float* Woh = (const float*)d_in[15]; const float* boh = (const float*)d_in[16];
    const float* Wux = (const float*)d_in[17]; const float* bux = (const float*)d_in[18];
    const float* Wuh = (const float*)d_in[19]; const float* buh = (const float*)d_in[20];
    float* c_out = (float*)d_out;
    char* ws = (char*)d_ws;

    unsigned short* fxb   = (unsigned short*)(ws + FXB_OFF);
    unsigned short* hsumb = (unsigned short*)(ws + HSB_OFF);
    float*          fcs   = (float*)(ws + FCS_OFF);
    unsigned short* bpx   = (unsigned short*)(ws + BPX_OFF);
    unsigned short* bph   = (unsigned short*)(ws + BPH_OFF);

    pack_w<<<128, 512, 0, stream>>>(Wix, Wox, Wux, Wfx, Wih, Woh, Wuh, Wfh, bpx, bph);
    fx32<<<(NINT + 63) / 64, 640, 0, stream>>>(tokens, emb, bfx, bpx, fxb);

    static const int bases[7] = {0, 1, 9, 73, 585, 4681, 37449};
    static const int cnts[7]  = {1, 8, 64, 512, 4096, 32768, 262144};

    level32<false><<<cnts[6] / 64, 640, 0, stream>>>(
        tokens, emb, bix, bih, box_, boh, bux, buh, bfh,
        bpx, bph, fxb, hsumb, fcs, c_out, bases[6], cnts[6], 1);
    for (int d = 5; d >= 0; --d) {
        int grid = (cnts[d] + 63) / 64;
        level32<true><<<grid, 640, 0, stream>>>(
            tokens, emb, bix, bih, box_, boh, bux, buh, bfh,
            bpx, bph, fxb, hsumb, fcs, c_out, bases[d], cnts[d], (d > 0) ? 1 : 0);
    }
}

// Round 7
// 297.290 us; speedup vs baseline: 3.1995x; 1.5893x over previous
//
#include <hip/hip_runtime.h>

// ChildSumTreeLSTM, complete 8-ary tree, 7 levels, N=299593, MEM=150, IN=300.
// Level d occupies [(8^d-1)/7, (8^(d+1)-1)/7); children of p: 8p+1..8p+8.
// v7: x-side projections precomputed PER VOCAB ENTRY (50000 rows) into an
// interleaved bf16 table gall[v][152][4] = {Wix·x+bix+bih, Wox·x+box+boh,
// Wux·x+bux+buh, Wfx·x+bfx+bfh}. Level kernels gather instead of GEMM on the
// x side; only h-side GEMMs (hsum gates, fh) remain as MFMA.

#define MEMD  150
#define IND   300
#define NINT  37449
#define VOCAB 50000
#define GROW  608          // ushorts per gall row: 152 cols x 4 gates
#define FSTR  152          // hsum/fcsum row stride (elements)

typedef short bf16x8 __attribute__((ext_vector_type(8)));
typedef float f32x16 __attribute__((ext_vector_type(16)));
#define ZERO16 {0,0,0,0,0,0,0,0,0,0,0,0,0,0,0,0}

// ws layout (bytes), total 95,584,800 <= 95.87MB proven available
#define GALL_OFF 0ul           // ushort [VOCAB][152][4]       60,800,000
#define HSB_OFF  60800000ul    // bf16  [NINT][152] h_sum      11,384,496
#define FCS_OFF  72200000ul    // f32   [NINT][152] sum f*c    22,768,992
#define BPX_OFF  94980000ul    // bf16 B-frags x-side [4][5][19][64][8]
#define BPH_OFF  95380000ul    // bf16 B-frags h-side [4][5][10][64][8]

__device__ __forceinline__ float b2f(unsigned short u) {
    union { unsigned int i; float f; } v; v.i = ((unsigned int)u) << 16; return v.f;
}
__device__ __forceinline__ unsigned short f2b(float f) {
    union { float f; unsigned int i; } v; v.f = f;
    unsigned int x = v.i;
    x += 0x7fffu + ((x >> 16) & 1u);
    return (unsigned short)(x >> 16);
}
__device__ __forceinline__ float sigm(float x) {
    return __builtin_amdgcn_rcpf(1.0f + __expf(-x));
}
__device__ __forceinline__ float tanh_fast(float x) {
    float e = __expf(2.0f * x);
    return 1.0f - 2.0f * __builtin_amdgcn_rcpf(e + 1.0f);
}

// ---- pack weights into 32x32x16 B-fragment order (verified R3-R6) ----
__global__ void pack_w(const float* __restrict__ Wix, const float* __restrict__ Wox,
                       const float* __restrict__ Wux, const float* __restrict__ Wfx,
                       const float* __restrict__ Wih, const float* __restrict__ Woh,
                       const float* __restrict__ Wuh, const float* __restrict__ Wfh,
                       unsigned short* __restrict__ bpx, unsigned short* __restrict__ bph)
{
    const int total_x = 4 * 5 * 19 * 512;
    const int total_h = 4 * 5 * 10 * 512;
    for (int i = blockIdx.x * blockDim.x + threadIdx.x; i < total_x + total_h;
         i += gridDim.x * blockDim.x) {
        if (i < total_x) {
            int e = i & 7, lane = (i >> 3) & 63, rest = i >> 9;
            int ks = rest % 19; rest /= 19;
            int nt = rest % 5;  int g = rest / 5;
            int col = nt * 32 + (lane & 31);
            int k = ks * 16 + ((lane >> 5) << 3) + e;
            const float* W = (g == 0) ? Wix : (g == 1) ? Wox : (g == 2) ? Wux : Wfx;
            bpx[i] = f2b((col < MEMD && k < IND) ? W[col * IND + k] : 0.f);
        } else {
            int j = i - total_x;
            int e = j & 7, lane = (j >> 3) & 63, rest = j >> 9;
            int ks = rest % 10; rest /= 10;
            int nt = rest % 5;  int g = rest / 5;
            int col = nt * 32 + (lane & 31);
            int k = ks * 16 + ((lane >> 5) << 3) + e;
            const float* W = (g == 0) ? Wih : (g == 1) ? Woh : (g == 2) ? Wuh : Wfh;
            bph[j] = f2b((col < MEMD && k < MEMD) ? W[col * MEMD + k] : 0.f);
        }
    }
}

// ---- per-vocab gate projections: gall[v][col][g], biases folded ----
__global__ __launch_bounds__(640, 2)
void vocab_gemm(const float* __restrict__ emb,
                const float* __restrict__ bix, const float* __restrict__ bih,
                const float* __restrict__ box_, const float* __restrict__ boh,
                const float* __restrict__ bux, const float* __restrict__ buh,
                const float* __restrict__ bfx, const float* __restrict__ bfh,
                const unsigned short* __restrict__ bpx_u,
                unsigned short* __restrict__ gall)
{
    __shared__ __align__(16) char sm0[40960];
    const int tid = threadIdx.x, lane = tid & 63, w = tid >> 6;
    const int hi = lane >> 5, ln31 = lane & 31;
    const int tile0 = blockIdx.x * 64;
    const int rowsValid = min(64, VOCAB - tile0);
    const int mt = (w >= 5) ? 1 : 0, nt = w - mt * 5;

    // stage 64 emb rows -> bf16 LDS, swizzled (chunks of 8 elems = 16B)
    for (int i = tid; i < 64 * 40; i += 640) {
        int r = i / 40, q = i % 40;
        int rr = (r < rowsValid) ? r : 0;
        const float* er = emb + (long)(tile0 + rr) * IND;
        float4 v0 = {0.f,0.f,0.f,0.f}, v1 = {0.f,0.f,0.f,0.f};
        if (q < 38) v0 = *(const float4*)(er + q * 8);
        if (q < 37) v1 = *(const float4*)(er + q * 8 + 4);
        bf16x8 p;
        p[0]=(short)f2b(v0.x); p[1]=(short)f2b(v0.y); p[2]=(short)f2b(v0.z); p[3]=(short)f2b(v0.w);
        p[4]=(short)f2b(v1.x); p[5]=(short)f2b(v1.y); p[6]=(short)f2b(v1.z); p[7]=(short)f2b(v1.w);
        *(bf16x8*)(sm0 + r * 640 + ((q * 16) ^ ((r & 7) << 4))) = p;
    }
    __syncthreads();

    const bf16x8* BX = (const bf16x8*)bpx_u;
    const int row = mt * 32 + ln31;
    const int col = nt * 32 + ln31;
    const bool colv = col < MEMD;
    const int cc = colv ? col : 0;
    const float* b1[4] = {bix, box_, bux, bfx};
    const float* b2[4] = {bih, boh, buh, bfh};

    for (int g = 0; g < 4; ++g) {
        f32x16 acc = ZERO16;
        bf16x8 aC = *(const bf16x8*)(sm0 + row * 640 + ((0) ^ ((row & 7) << 4)));
        bf16x8 bC = BX[((g * 5 + nt) * 19 + 0) * 64 + lane];
        #pragma unroll
        for (int ks = 0; ks < 19; ++ks) {
            bf16x8 aN, bN;
            if (ks < 18) {
                aN = *(const bf16x8*)(sm0 + row * 640 + (((ks + 1) * 32 + hi * 16) ^ ((row & 7) << 4)));
                bN = BX[((g * 5 + nt) * 19 + ks + 1) * 64 + lane];
            }
            if (ks == 0) aC = *(const bf16x8*)(sm0 + row * 640 + ((hi * 16) ^ ((row & 7) << 4)));
            acc = __builtin_amdgcn_mfma_f32_32x32x16_bf16(aC, bC, acc, 0, 0, 0);
            aC = aN; bC = bN;
        }
        float bias = colv ? (b1[g][cc] + b2[g][cc]) : 0.f;
        #pragma unroll
        for (int r = 0; r < 16; ++r) {
            int rloc = mt * 32 + (r & 3) + 8 * (r >> 2) + 4 * hi;
            if (rloc < rowsValid && colv)
                gall[(long)(tile0 + rloc) * GROW + col * 4 + g] = f2b(acc[r] + bias);
        }
    }
}

// ---- per-level kernel: x side gathered from gall; h side MFMA ----
template<bool INTERNAL>
__global__ __launch_bounds__(320, INTERNAL ? 2 : 4)
void level_k(const int* __restrict__ tokens,
             const unsigned short* __restrict__ gall,
             const unsigned short* __restrict__ bph_u,
             unsigned short* __restrict__ hsumb, float* __restrict__ fcsum,
             float* __restrict__ c_out, int base, int cnt, int writePar)
{
    // LDS: hsL [0,12288) 32x384B swizzled; (INTERNAL) hsumL [12288,24576)
    __shared__ __align__(16) char sm0[INTERNAL ? 24576 : 12288];
    __shared__ int toksL[32];
    __shared__ int ptokL[4];
    const int tid = threadIdx.x, lane = tid & 63, w = tid >> 6;
    const int hi = lane >> 5, ln31 = lane & 31;
    const int tile0 = blockIdx.x * 32;
    const int nodeBase = base + tile0;
    const int rowsValid = min(32, cnt - tile0);
    const int p0 = (nodeBase - 1) >> 3;
    const int nt = w;          // 5 waves, one 32-col tile each

    if (tid < 32) toksL[tid] = tokens[nodeBase + ((tid < rowsValid) ? tid : 0)];
    if (writePar && tid < 4) ptokL[tid] = tokens[p0 + tid];
    if (INTERNAL) {
        for (int i = tid; i < 32 * 20; i += 320) {
            int r = i / 20, q = i % 20;
            bf16x8 v = {0,0,0,0,0,0,0,0};
            if (q < 19)
                v = *(const bf16x8*)(hsumb + (long)(nodeBase + r) * FSTR + q * 8);
            *(bf16x8*)(sm0 + 12288 + r * 384 + ((q * 16) ^ ((r & 7) << 4))) = v;
        }
    }
    __syncthreads();

    const bf16x8* BH = (const bf16x8*)bph_u;
    const int row = ln31;
    const int col = nt * 32 + ln31;
    const bool colv = col < MEMD;
    const int cc = colv ? col : 0;

    // ---- h_sum-side gate GEMM (internal only) ----
    f32x16 ai = ZERO16, ao = ZERO16, au = ZERO16;
    if (INTERNAL) {
        const char* hb = sm0 + 12288;
        bf16x8 aC = *(const bf16x8*)(hb + row * 384 + ((hi * 16) ^ ((row & 7) << 4)));
        bf16x8 b0C = BH[((0 * 5 + nt) * 10 + 0) * 64 + lane];
        bf16x8 b1C = BH[((1 * 5 + nt) * 10 + 0) * 64 + lane];
        bf16x8 b2C = BH[((2 * 5 + nt) * 10 + 0) * 64 + lane];
        #pragma unroll
        for (int ks = 0; ks < 10; ++ks) {
            bf16x8 aN, b0N, b1N, b2N;
            if (ks < 9) {
                aN  = *(const bf16x8*)(hb + row * 384 + (((ks + 1) * 32 + hi * 16) ^ ((row & 7) << 4)));
                b0N = BH[((0 * 5 + nt) * 10 + ks + 1) * 64 + lane];
                b1N = BH[((1 * 5 + nt) * 10 + ks + 1) * 64 + lane];
                b2N = BH[((2 * 5 + nt) * 10 + ks + 1) * 64 + lane];
            }
            ai = __builtin_amdgcn_mfma_f32_32x32x16_bf16(aC, b0C, ai, 0, 0, 0);
            ao = __builtin_amdgcn_mfma_f32_32x32x16_bf16(aC, b1C, ao, 0, 0, 0);
            au = __builtin_amdgcn_mfma_f32_32x32x16_bf16(aC, b2C, au, 0, 0, 0);
            aC = aN; b0C = b0N; b1C = b1N; b2C = b2N;
        }
    }

    // ---- epilogue: gather x-side pre-activations, gates, c, h ----
    float cvv[16];
    {
        ushort4 gv[16];
        #pragma unroll
        for (int r = 0; r < 16; ++r) {
            int rloc = (r & 3) + 8 * (r >> 2) + 4 * hi;
            gv[r] = *(const ushort4*)(gall + (long)toksL[rloc] * GROW + cc * 4);
        }
        float hp[4] = {0.f, 0.f, 0.f, 0.f};
        #pragma unroll
        for (int r = 0; r < 16; ++r) {
            int rloc = (r & 3) + 8 * (r >> 2) + 4 * hi;
            bool rv = rloc < rowsValid;
            float fc = 0.f;
            if (INTERNAL) fc = (rv && colv) ? fcsum[(long)(nodeBase + rloc) * FSTR + col] : 0.f;
            float iv = sigm((INTERNAL ? ai[r] : 0.f) + b2f(gv[r].x));
            float ov = sigm((INTERNAL ? ao[r] : 0.f) + b2f(gv[r].y));
            float uv = tanh_fast((INTERNAL ? au[r] : 0.f) + b2f(gv[r].z));
            float cv = iv * uv + fc;
            float h = (rv && colv) ? ov * tanh_fast(cv) : 0.f;
            cvv[r] = (rv && colv) ? cv : 0.f;
            if (rv && colv) c_out[(long)(nodeBase + rloc) * MEMD + col] = cv;
            *(unsigned short*)(sm0 + rloc * 384 + ((col * 2) ^ ((rloc & 7) << 4))) = f2b(h);
            hp[r >> 2] += h;
        }
        if (writePar) {
            #pragma unroll
            for (int o = 0; o < 4; ++o) {
                float s = hp[o] + __shfl_xor(hp[o], 32);
                if (lane < 32 && colv && o * 8 < rowsValid)
                    hsumb[(long)(p0 + o) * FSTR + col] = f2b(s);
            }
        }
    }
    __syncthreads();   // hsL complete

    if (writePar) {
        // ---- fh = h @ Wfh^T; f*c from register cvv; octet reduce ----
        f32x16 ff = ZERO16;
        {
            bf16x8 aC = *(const bf16x8*)(sm0 + row * 384 + ((hi * 16) ^ ((row & 7) << 4)));
            bf16x8 bC = BH[((15 + nt) * 10 + 0) * 64 + lane];
            #pragma unroll
            for (int ks = 0; ks < 10; ++ks) {
                bf16x8 aN, bN;
                if (ks < 9) {
                    aN = *(const bf16x8*)(sm0 + row * 384 + (((ks + 1) * 32 + hi * 16) ^ ((row & 7) << 4)));
                    bN = BH[((15 + nt) * 10 + ks + 1) * 64 + lane];
                }
                ff = __builtin_amdgcn_mfma_f32_32x32x16_bf16(aC, bC, ff, 0, 0, 0);
                aC = aN; bC = bN;
            }
        }
        #pragma unroll
        for (int o = 0; o < 4; ++o) {
            float fx = b2f(gall[(long)ptokL[o] * GROW + cc * 4 + 3]);
            float fp = 0.f;
            #pragma unroll
            for (int q = 0; q < 4; ++q) {
                int r = o * 4 + q;
                fp += sigm(ff[r] + fx) * cvv[r];
            }
            float s = fp + __shfl_xor(fp, 32);
            if (lane < 32 && colv && o * 8 < rowsValid)
                fcsum[(long)(p0 + o) * FSTR + col] = s;
        }
    }
}

extern "C" void kernel_launch(void* const* d_in, const int* in_sizes, int n_in,
                              void* d_out, int out_size, void* d_ws, size_t ws_size,
                              hipStream_t stream) {
    const int*   tokens = (const int*)d_in[0];
    const float* emb = (const float*)d_in[4];
    const float* Wix = (const float*)d_in[5];  const float* bix = (const float*)d_in[6];
    const float* Wih = (const float*)d_in[7];  const float* bih = (const float*)d_in[8];
    const float* Wfx = (const float*)d_in[9];  const float* bfx = (const float*)d_in[10];
    const float* Wfh = (const float*)d_in[11]; const float* bfh = (const float*)d_in[12];
    const float* Wox = (const float*)d_in[13]; const float* box_ = (const float*)d_in[14];
    const float* Woh = (const float*)d_in[15]; const float* boh = (const float*)d_in[16];
    const float* Wux = (const float*)d_in[17]; const float* bux = (const float*)d_in[18];
    const float* Wuh = (const float*)d_in[19]; const float* buh = (const float*)d_in[20];
    float* c_out = (float*)d_out;
    char* ws = (char*)d_ws;

    unsigned short* gall  = (unsigned short*)(ws + GALL_OFF);
    unsigned short* hsumb = (unsigned short*)(ws + HSB_OFF);
    float*          fcs   = (float*)(ws + FCS_OFF);
    unsigned short* bpx   = (unsigned short*)(ws + BPX_OFF);
    unsigned short* bph   = (unsigned short*)(ws + BPH_OFF);

    pack_w<<<128, 512, 0, stream>>>(Wix, Wox, Wux, Wfx, Wih, Woh, Wuh, Wfh, bpx, bph);
    vocab_gemm<<<(VOCAB + 63) / 64, 640, 0, stream>>>(
        emb, bix, bih, box_, boh, bux, buh, bfx, bfh, bpx, gall);

    static const int bases[7] = {0, 1, 9, 73, 585, 4681, 37449};
    static const int cnts[7]  = {1, 8, 64, 512, 4096, 32768, 262144};

    level_k<false><<<cnts[6] / 32, 320, 0, stream>>>(
        tokens, gall, bph, hsumb, fcs, c_out, bases[6], cnts[6], 1);
    for (int d = 5; d >= 0; --d) {
        int grid = (cnts[d] + 31) / 32;
        level_k<true><<<grid, 320, 0, stream>>>(
            tokens, gall, bph, hsumb, fcs, c_out, bases[d], cnts[d], (d > 0) ? 1 : 0);
    }
}